// Round 1
// baseline (689.690 us; speedup 1.0000x reference)
//
#include <hip/hip_runtime.h>

#define N_NODES 50000
#define N_EDGES 1600000
#define F 32

// Workspace layout (floats):
//   node_sum / node_mean : N_NODES * F   (reused in place)
//   node_h               : N_NODES * F
//   in_deg               : N_NODES

// Stage 1: node_sum[dst[e]][f] += inputs[e][f];  in_deg[dst[e]] += 1
__global__ void k_scatter_sum_deg(const float* __restrict__ inputs,
                                  const int* __restrict__ dst,
                                  float* __restrict__ node_sum,
                                  float* __restrict__ in_deg) {
    int tid = blockIdx.x * blockDim.x + threadIdx.x;   // e*32 + f
    if (tid >= N_EDGES * F) return;
    int e = tid >> 5;
    int f = tid & 31;
    int d = dst[e];
    atomicAdd(&node_sum[d * F + f], inputs[tid]);
    if (f == 0) atomicAdd(&in_deg[d], 1.0f);
}

// Stage 2: node_mean = node_sum / max(in_deg, 1)   (in place)
__global__ void k_mean(float* __restrict__ node_sum,
                       const float* __restrict__ in_deg) {
    int tid = blockIdx.x * blockDim.x + threadIdx.x;   // n*32 + f
    if (tid >= N_NODES * F) return;
    int n = tid >> 5;
    node_sum[tid] = node_sum[tid] / fmaxf(in_deg[n], 1.0f);
}

// Stage 3: node_h[dst[e]][f] += node_mean[src[e]][f]
__global__ void k_scatter_h(const int* __restrict__ src,
                            const int* __restrict__ dst,
                            const float* __restrict__ node_mean,
                            float* __restrict__ node_h) {
    int tid = blockIdx.x * blockDim.x + threadIdx.x;   // e*32 + f
    if (tid >= N_EDGES * F) return;
    int e = tid >> 5;
    int f = tid & 31;
    int s = src[e];
    int d = dst[e];
    atomicAdd(&node_h[d * F + f], node_mean[s * F + f]);
}

// Stage 4: out[e] = (0.5*(node_h[src[e]] + node_h[dst[e]])) @ W^T + b
// 256 threads = 8 edges/block. edge_h staged in LDS (stride-1, conflict-free).
// W staged in LDS with +1 pad so lanes (varying o) read distinct banks.
__global__ void k_edge_out(const int* __restrict__ src,
                           const int* __restrict__ dst,
                           const float* __restrict__ node_h,
                           const float* __restrict__ W,
                           const float* __restrict__ b,
                           float* __restrict__ out) {
    __shared__ float Wl[32][33];
    __shared__ float bl[32];
    __shared__ float eh[8][32];

    int tid = threadIdx.x;
    // Cooperative load of W (1024 floats) and b (32 floats) into LDS.
    #pragma unroll
    for (int i = tid; i < 1024; i += 256) {
        Wl[i >> 5][i & 31] = W[i];
    }
    if (tid < 32) bl[tid] = b[tid];

    int le = tid >> 5;       // local edge 0..7
    int f  = tid & 31;       // feature / output channel
    int e  = blockIdx.x * 8 + le;

    float v = 0.0f;
    if (e < N_EDGES) {
        int s = src[e];
        int d = dst[e];
        v = 0.5f * (node_h[s * F + f] + node_h[d * F + f]);
    }
    eh[le][f] = v;
    __syncthreads();

    if (e < N_EDGES) {
        float acc = bl[f];
        #pragma unroll
        for (int i = 0; i < 32; ++i) {
            acc += eh[le][i] * Wl[f][i];
        }
        out[e * F + f] = acc;
    }
}

extern "C" void kernel_launch(void* const* d_in, const int* in_sizes, int n_in,
                              void* d_out, int out_size, void* d_ws, size_t ws_size,
                              hipStream_t stream) {
    const float* inputs = (const float*)d_in[0];
    const int*   src    = (const int*)d_in[1];
    const int*   dst    = (const int*)d_in[2];
    const float* W      = (const float*)d_in[3];
    const float* b      = (const float*)d_in[4];
    float* out = (float*)d_out;

    float* node_sum = (float*)d_ws;                       // N*F (becomes node_mean)
    float* node_h   = node_sum + (size_t)N_NODES * F;     // N*F
    float* in_deg   = node_h   + (size_t)N_NODES * F;     // N

    size_t zero_bytes = ((size_t)N_NODES * F * 2 + N_NODES) * sizeof(float);
    hipMemsetAsync(d_ws, 0, zero_bytes, stream);

    int total_ef = N_EDGES * F;
    k_scatter_sum_deg<<<(total_ef + 255) / 256, 256, 0, stream>>>(
        inputs, dst, node_sum, in_deg);
    k_mean<<<(N_NODES * F + 255) / 256, 256, 0, stream>>>(
        node_sum, in_deg);
    k_scatter_h<<<(total_ef + 255) / 256, 256, 0, stream>>>(
        src, dst, node_sum, node_h);
    k_edge_out<<<(N_EDGES + 7) / 8, 256, 0, stream>>>(
        src, dst, node_h, W, b, out);
}

// Round 2
// 511.105 us; speedup vs baseline: 1.3494x; 1.3494x over previous
//
#include <hip/hip_runtime.h>

#define N_NODES 50000
#define N_EDGES 1600000
#define F 32

// Workspace layout (floats):
//   node_sum / node_mean : N_NODES * F   (reused in place)
//   node_h               : N_NODES * F
//   node_p               : N_NODES * F
//   in_deg               : N_NODES

// Stage 1: node_sum[dst[e]][f] += inputs[e][f];  in_deg[dst[e]] += 1
__global__ void k_scatter_sum_deg(const float* __restrict__ inputs,
                                  const int* __restrict__ dst,
                                  float* __restrict__ node_sum,
                                  float* __restrict__ in_deg) {
    int tid = blockIdx.x * blockDim.x + threadIdx.x;   // e*32 + f
    if (tid >= N_EDGES * F) return;
    int e = tid >> 5;
    int f = tid & 31;
    int d = dst[e];
    atomicAdd(&node_sum[d * F + f], inputs[tid]);
    if (f == 0) atomicAdd(&in_deg[d], 1.0f);
}

// Stage 2: node_mean = node_sum / max(in_deg, 1)   (in place)
__global__ void k_mean(float* __restrict__ node_sum,
                       const float* __restrict__ in_deg) {
    int tid = blockIdx.x * blockDim.x + threadIdx.x;   // n*32 + f
    if (tid >= N_NODES * F) return;
    int n = tid >> 5;
    node_sum[tid] = node_sum[tid] / fmaxf(in_deg[n], 1.0f);
}

// Stage 3: node_h[dst[e]][f] += node_mean[src[e]][f]
__global__ void k_scatter_h(const int* __restrict__ src,
                            const int* __restrict__ dst,
                            const float* __restrict__ node_mean,
                            float* __restrict__ node_h) {
    int tid = blockIdx.x * blockDim.x + threadIdx.x;   // e*32 + f
    if (tid >= N_EDGES * F) return;
    int e = tid >> 5;
    int f = tid & 31;
    int s = src[e];
    int d = dst[e];
    atomicAdd(&node_h[d * F + f], node_mean[s * F + f]);
}

// Stage 3.5: node_p = node_h @ W^T  (50K x 32 rows, tiny)
__global__ void k_project(const float* __restrict__ node_h,
                          const float* __restrict__ W,
                          float* __restrict__ node_p) {
    __shared__ float Wl[32][33];
    __shared__ float hr[8][32];

    int tid = threadIdx.x;
    #pragma unroll
    for (int i = tid; i < 1024; i += 256) {
        Wl[i >> 5][i & 31] = W[i];
    }

    int ln = tid >> 5;      // local node 0..7
    int o  = tid & 31;      // output channel
    int n  = blockIdx.x * 8 + ln;

    float v = 0.0f;
    if (n < N_NODES) v = node_h[n * F + o];
    hr[ln][o] = v;
    __syncthreads();

    if (n < N_NODES) {
        float acc = 0.0f;
        #pragma unroll
        for (int i = 0; i < 32; ++i) {
            acc += hr[ln][i] * Wl[o][i];
        }
        node_p[n * F + o] = acc;
    }
}

// Stage 4: out[e] = 0.5*(node_p[src[e]] + node_p[dst[e]]) + b
// One thread per (edge, float4 quad): pure gather + add + streaming write.
__global__ void k_edge_out(const int* __restrict__ src,
                           const int* __restrict__ dst,
                           const float* __restrict__ node_p,
                           const float* __restrict__ b,
                           float* __restrict__ out) {
    int tid = blockIdx.x * blockDim.x + threadIdx.x;   // e*8 + q
    if (tid >= N_EDGES * 8) return;
    int e = tid >> 3;
    int q = tid & 7;
    int s = src[e];
    int d = dst[e];

    const float4 a  = *reinterpret_cast<const float4*>(&node_p[s * F + q * 4]);
    const float4 c  = *reinterpret_cast<const float4*>(&node_p[d * F + q * 4]);
    const float4 bb = *reinterpret_cast<const float4*>(&b[q * 4]);

    float4 r;
    r.x = 0.5f * (a.x + c.x) + bb.x;
    r.y = 0.5f * (a.y + c.y) + bb.y;
    r.z = 0.5f * (a.z + c.z) + bb.z;
    r.w = 0.5f * (a.w + c.w) + bb.w;

    *reinterpret_cast<float4*>(&out[e * F + q * 4]) = r;
}

extern "C" void kernel_launch(void* const* d_in, const int* in_sizes, int n_in,
                              void* d_out, int out_size, void* d_ws, size_t ws_size,
                              hipStream_t stream) {
    const float* inputs = (const float*)d_in[0];
    const int*   src    = (const int*)d_in[1];
    const int*   dst    = (const int*)d_in[2];
    const float* W      = (const float*)d_in[3];
    const float* b      = (const float*)d_in[4];
    float* out = (float*)d_out;

    float* node_sum = (float*)d_ws;                       // N*F (becomes node_mean)
    float* node_h   = node_sum + (size_t)N_NODES * F;     // N*F
    float* node_p   = node_h   + (size_t)N_NODES * F;     // N*F
    float* in_deg   = node_p   + (size_t)N_NODES * F;     // N

    // Zero node_sum, node_h, in_deg (node_p is overwritten, no zero needed,
    // but it sits between node_h and in_deg, so zero the whole span).
    size_t zero_bytes = ((size_t)N_NODES * F * 3 + N_NODES) * sizeof(float);
    hipMemsetAsync(d_ws, 0, zero_bytes, stream);

    int total_ef = N_EDGES * F;
    k_scatter_sum_deg<<<(total_ef + 255) / 256, 256, 0, stream>>>(
        inputs, dst, node_sum, in_deg);
    k_mean<<<(N_NODES * F + 255) / 256, 256, 0, stream>>>(
        node_sum, in_deg);
    k_scatter_h<<<(total_ef + 255) / 256, 256, 0, stream>>>(
        src, dst, node_sum, node_h);
    k_project<<<(N_NODES + 7) / 8, 256, 0, stream>>>(
        node_h, W, node_p);
    k_edge_out<<<(N_EDGES * 8 + 255) / 256, 256, 0, stream>>>(
        src, dst, node_p, b, out);
}